// Round 3
// baseline (4746.650 us; speedup 1.0000x reference)
//
#include <hip/hip_runtime.h>
#include <math.h>

#define XDIM 521
#define TDIM 49
#define TPAD 52
#define XT (XDIM*TPAD)   /* 27092 */
#define NBTOT 32
#define NC 64
#define NS 512
#define NTO 40
#define NTIN 10
#define CIN 14
#define PI_D 3.14159265358979323846

__device__ __forceinline__ float gelu_f(float x){
  return 0.5f*x*(1.0f + erff(x*0.70710678118654752440f));
}

// ---------------- init: twiddle tables + small transposed weight copies ----------------
__global__ void k_init(float* __restrict__ TXC, float* __restrict__ TXS,
                       float* __restrict__ TTC, float* __restrict__ TTS,
                       float* __restrict__ ITC, float* __restrict__ ITS,
                       float* __restrict__ WT0, float* __restrict__ WT1, float* __restrict__ WTC,
                       const float* __restrict__ fc0_w, const float* __restrict__ fc1_w,
                       const float* __restrict__ w_conv){
  int i = blockIdx.x*256 + threadIdx.x;
  if (i < XDIM*16){
    int x = i >> 4, kx = i & 15;
    double ang = 2.0*PI_D*(double)((x*kx)%XDIM)/(double)XDIM;
    TXC[i] = (float)cos(ang);
    TXS[i] = (float)sin(ang);
  }
  if (i < TDIM*16){
    int t = i >> 4, kt = i & 15;
    double ang = 2.0*PI_D*(double)((t*kt)%TDIM)/(double)TDIM;
    TTC[i] = (float)cos(ang);
    TTS[i] = (float)sin(ang);
    double nrm = ((kt==0)?1.0:2.0)/(double)(XDIM*TDIM);
    ITC[i] = (float)(nrm*cos(ang));
    ITS[i] = (float)(nrm*sin(ang));
  }
  if (i < 64*16){               // fc0_w (14,64) -> WT0[c][16]
    int c = i >> 4, k = i & 15;
    WT0[i] = (k < CIN) ? fc0_w[k*64 + c] : 0.f;
  }
  if (i < 128*64){              // fc1_w (64,128) -> WT1[j][c]
    int j = i >> 6, c = i & 63;
    WT1[i] = fc1_w[c*128 + j];
  }
  if (i < 4*64*64){             // w_conv (4,o,c) -> WTC[l][c][o]
    int l = i >> 12, r = i & 4095, c = r >> 6, o = r & 63;
    WTC[i] = w_conv[(l*64 + o)*64 + c];
  }
}

// ---------------- fc0 + grid-feature build + transpose + pad (writes chunk VA) ----------------
__global__ void k_fc0(const float* __restrict__ u, const float* __restrict__ xg,
                      const float* __restrict__ tg, const float* __restrict__ par,
                      const float* __restrict__ WT0, const float* __restrict__ fc0_b,
                      float* __restrict__ v, int b0){
  int bl = blockIdx.y;          // local batch within chunk
  int b  = b0 + bl;             // global batch
  int p = blockIdx.x*256 + threadIdx.x;
  if (p >= XT) return;
  int x = p / TPAD, t = p - x*TPAD;
  bool valid = (x < NS) && (t < NTO);
  float in[CIN];
  if (valid){
    #pragma unroll
    for (int k=0;k<NTIN;k++) in[k] = u[((size_t)(b*NS+x))*NTIN + k];
    in[10] = par[b*2+0]; in[11] = par[b*2+1];
    in[12] = xg[b*NS + x];
    in[13] = tg[b*NTO + t];
  } else {
    #pragma unroll
    for (int k=0;k<CIN;k++) in[k] = 0.f;
  }
  size_t base = ((size_t)bl*NC)*XT + p;
  for (int c=0;c<NC;c++){
    float acc = valid ? fc0_b[c] : 0.f;
    #pragma unroll
    for (int k=0;k<CIN;k++) acc = fmaf(in[k], WT0[c*16+k], acc);
    v[base + (size_t)c*XT] = acc;
  }
}

// ---------------- forward DFT over X (contract 521 -> 16 modes) ----------------
// one wave per (bl,c); lane = t (49 active); 16 complex accumulators
__global__ void __launch_bounds__(64) k_dftx(const float* __restrict__ v,
    const float* __restrict__ TXC, const float* __restrict__ TXS,
    float* __restrict__ VxR, float* __restrict__ VxI){
  int bo = blockIdx.x;
  int t = threadIdx.x;
  const float* vb = v + (size_t)bo*XT;
  bool act = (t < TDIM);
  float ar[16], ai[16];
  #pragma unroll
  for (int k=0;k<16;k++){ ar[k]=0.f; ai[k]=0.f; }
  #pragma unroll 2
  for (int x=0; x<XDIM; x++){
    float vv = act ? vb[(size_t)x*TPAD + t] : 0.f;
    #pragma unroll
    for (int kx=0;kx<16;kx++){
      ar[kx] = fmaf(vv,  TXC[x*16+kx], ar[kx]);
      ai[kx] = fmaf(-vv, TXS[x*16+kx], ai[kx]);
    }
  }
  if (act){
    #pragma unroll
    for (int kx=0;kx<16;kx++){
      VxR[((size_t)bo*16+kx)*TDIM + t] = ar[kx];
      VxI[((size_t)bo*16+kx)*TDIM + t] = ai[kx];
    }
  }
}

// ---------------- forward DFT over T (49 -> 16 modes), complex ----------------
__global__ void k_dftt(const float* __restrict__ VxR, const float* __restrict__ VxI,
                       const float* __restrict__ TTC, const float* __restrict__ TTS,
                       float* __restrict__ cVR, float* __restrict__ cVI, int NCB){
  int bo = blockIdx.x;
  __shared__ float lr[784], li[784];
  for (int q = threadIdx.x; q < 784; q += 256){ lr[q] = VxR[(size_t)bo*784+q]; li[q] = VxI[(size_t)bo*784+q]; }
  __syncthreads();
  int kx = threadIdx.x >> 4, kt = threadIdx.x & 15;
  float accR=0.f, accI=0.f;
  for (int tt=0;tt<TDIM;tt++){
    float vr = lr[kx*TDIM+tt], vi = li[kx*TDIM+tt];
    float c = TTC[tt*16+kt], s = TTS[tt*16+kt];
    accR += vr*c + vi*s;
    accI += vi*c - vr*s;
  }
  int m = kx*16+kt;
  cVR[(size_t)m*NCB + bo] = accR;
  cVI[(size_t)m*NCB + bo] = accI;
}

// ---------------- per-mode 64x64 complex channel mix (weights read in-place) ----------------
__global__ void k_spec(const float* __restrict__ swr, const float* __restrict__ swi,
                       const float* __restrict__ cVR, const float* __restrict__ cVI,
                       float* __restrict__ cOR, float* __restrict__ cOI, int l, int NCB){
  int m = blockIdx.x;           // 0..255 = kx*16+kt
  __shared__ float wr[4096], wi[4096];
  __shared__ float vr[32*65], vi[32*65];
  // element (l,i,o,kx,kt) at ((l*64+i)*64+o)*256 + m ; q = i*64+o
  const size_t wb = (size_t)l*64*64*256 + m;
  for (int q = threadIdx.x; q < 4096; q += 256){
    wr[q] = swr[wb + (size_t)q*256];
    wi[q] = swi[wb + (size_t)q*256];
  }
  for (int q = threadIdx.x; q < NCB; q += 256){
    int b=q>>6, i=q&63;
    vr[b*65+i] = cVR[(size_t)m*NCB+q];
    vi[b*65+i] = cVI[(size_t)m*NCB+q];
  }
  __syncthreads();
  int b = threadIdx.x >> 3, og = threadIdx.x & 7;
  if (b*64 < NCB){
    float oR[8], oI[8];
    #pragma unroll
    for (int j=0;j<8;j++){ oR[j]=0.f; oI[j]=0.f; }
    for (int i=0;i<64;i++){
      float arv = vr[b*65+i], aiv = vi[b*65+i];
      #pragma unroll
      for (int j=0;j<8;j++){
        float wrv = wr[i*64 + og*8 + j], wiv = wi[i*64 + og*8 + j];
        oR[j] = fmaf(arv,wrv,fmaf(-aiv,wiv,oR[j]));
        oI[j] = fmaf(arv,wiv,fmaf( aiv,wrv,oI[j]));
      }
    }
    #pragma unroll
    for (int j=0;j<8;j++){
      cOR[(size_t)m*NCB + b*64 + og*8 + j] = oR[j];
      cOI[(size_t)m*NCB + b*64 + og*8 + j] = oI[j];
    }
  }
}

// ---------------- pointwise conv, IN-PLACE: v <- W*v + bias (u2 stored) ----------------
__global__ void __launch_bounds__(256) k_conv(float* __restrict__ v,
    const float* __restrict__ WTC, const float* __restrict__ w_bias, int l){
  int bl = blockIdx.y;
  int p = blockIdx.x*512 + threadIdx.x*2;
  if (p >= XT) return;
  const float* wl = WTC + l*4096;    // [c][o]
  float a0[64], a1[64];
  #pragma unroll
  for (int o=0;o<64;o++){ a0[o]=0.f; a1[o]=0.f; }
  const size_t bb = (size_t)bl*NC*XT;
  for (int c=0;c<NC;c++){
    const float2 vv = *reinterpret_cast<const float2*>(v + bb + (size_t)c*XT + p);
    #pragma unroll
    for (int o=0;o<64;o++){
      float wv = wl[c*64+o];          // uniform -> s_load
      a0[o] = fmaf(vv.x, wv, a0[o]);
      a1[o] = fmaf(vv.y, wv, a1[o]);
    }
  }
  #pragma unroll
  for (int o=0;o<64;o++){
    float bias = w_bias[l*64+o];
    float2 rr; rr.x = a0[o]+bias; rr.y = a1[o]+bias;
    *reinterpret_cast<float2*>(v + bb + (size_t)o*XT + p) = rr;
  }
}

// ---------------- inverse transform + RMW: v = [gelu](u1 + v) ----------------
template<int GELU>
__global__ void __launch_bounds__(128) k_inv(const float* __restrict__ cOR, const float* __restrict__ cOI,
    const float* __restrict__ TXC, const float* __restrict__ TXS,
    const float* __restrict__ ITC, const float* __restrict__ ITS,
    float* __restrict__ vout, int NCB){
  int bo = blockIdx.x;
  __shared__ float twc[128*17], tws[128*17];
  __shared__ float outb[128*TPAD];
  for (int xc = 0; xc < XDIM; xc += 128){
    int xlen = min(128, XDIM - xc);
    for (int q = threadIdx.x; q < xlen*16; q += 128){
      int xx = q >> 4, kx = q & 15;
      twc[xx*17+kx] = TXC[(xc+xx)*16+kx];
      tws[xx*17+kx] = TXS[(xc+xx)*16+kx];
    }
    __syncthreads();
    int x = threadIdx.x;
    if (x < xlen){
      float hr[16], hi[16];
      #pragma unroll
      for (int k2=0;k2<16;k2++){ hr[k2]=0.f; hi[k2]=0.f; }
      #pragma unroll 4
      for (int kx=0;kx<16;kx++){
        float ec = twc[x*17+kx], es = tws[x*17+kx];   // e^{+i 2pi kx x / 521}
        #pragma unroll
        for (int k2=0;k2<16;k2++){
          float cr = cOR[(size_t)(kx*16+k2)*NCB + bo];   // uniform -> s_load
          float ci = cOI[(size_t)(kx*16+k2)*NCB + bo];
          hr[k2] = fmaf(cr,ec,fmaf(-ci,es,hr[k2]));
          hi[k2] = fmaf(cr,es,fmaf( ci,ec,hi[k2]));
        }
      }
      for (int tt=0;tt<TDIM;tt++){
        float acc = 0.f;
        #pragma unroll
        for (int k2=0;k2<16;k2++) acc += hr[k2]*ITC[tt*16+k2] - hi[k2]*ITS[tt*16+k2];
        outb[x*TPAD+tt] = acc;
      }
    }
    __syncthreads();
    size_t gbase = (size_t)bo*XT + (size_t)xc*TPAD;
    int n = xlen*TPAD;
    for (int q = threadIdx.x; q < n; q += 128){
      int tt = q % TPAD;
      float r = 0.f;
      if (tt < TDIM){
        r = outb[q] + vout[gbase+q];
        if (GELU) r = gelu_f(r);
      }
      vout[gbase+q] = r;     // slack cols t=49..51 forced to 0
    }
    __syncthreads();
  }
}

// ---------------- crop + fc1 + gelu + fc2 ----------------
__global__ void k_final(const float* __restrict__ v, const float* __restrict__ WT1,
                        const float* __restrict__ fc1_b, const float* __restrict__ fc2_w,
                        const float* __restrict__ fc2_b, float* __restrict__ out, int b0){
  int bl = blockIdx.y;
  int pp = blockIdx.x*256 + threadIdx.x;    // 512*40 = 20480 exactly
  int s = pp / NTO, to = pp - s*NTO;
  float vr[64];
  size_t vb = (size_t)bl*NC*XT + (size_t)s*TPAD + to;
  #pragma unroll
  for (int c=0;c<64;c++) vr[c] = v[vb + (size_t)c*XT];
  float acc = fc2_b[0];
  for (int j=0;j<128;j++){
    float h = fc1_b[j];
    #pragma unroll
    for (int c=0;c<64;c++) h = fmaf(vr[c], WT1[j*64+c], h);   // uniform -> s_load
    h = gelu_f(h);
    acc = fmaf(h, fc2_w[j], acc);
  }
  out[((size_t)(b0+bl))*20480 + pp] = acc;
}

extern "C" void kernel_launch(void* const* d_in, const int* in_sizes, int n_in,
                              void* d_out, int out_size, void* d_ws, size_t ws_size,
                              hipStream_t stream){
  const float* u     = (const float*)d_in[0];
  const float* xg    = (const float*)d_in[1];
  const float* tg    = (const float*)d_in[2];
  const float* par   = (const float*)d_in[3];
  const float* fc0_w = (const float*)d_in[4];
  const float* fc0_b = (const float*)d_in[5];
  const float* swr   = (const float*)d_in[6];
  const float* swi   = (const float*)d_in[7];
  const float* wconv = (const float*)d_in[8];
  const float* wbias = (const float*)d_in[9];
  const float* fc1_w = (const float*)d_in[10];
  const float* fc1_b = (const float*)d_in[11];
  const float* fc2_w = (const float*)d_in[12];
  const float* fc2_b = (const float*)d_in[13];

  // pick largest batch chunk whose workspace fits ws_size (deterministic per session)
  int nb = NBTOT;
  while (nb > 1){
    size_t need = (45408ull + (size_t)nb*64ull*29684ull) * 4ull;
    if (need <= ws_size) break;
    nb >>= 1;
  }
  const int NCB = nb*64;

  float* W = (float*)d_ws;
  size_t off = 0;
  float* TXC = W + off; off += 8336;
  float* TXS = W + off; off += 8336;
  float* TTC = W + off; off += 784;
  float* TTS = W + off; off += 784;
  float* ITC = W + off; off += 784;
  float* ITS = W + off; off += 784;
  float* WT0 = W + off; off += 1024;
  float* WT1 = W + off; off += 8192;
  float* WTC = W + off; off += 16384;
  float* VA  = W + off; off += (size_t)NCB*XT;
  float* VXR = W + off; off += (size_t)NCB*784;
  float* VXI = W + off; off += (size_t)NCB*784;
  float* CVR = W + off; off += (size_t)256*NCB;
  float* CVI = W + off; off += (size_t)256*NCB;
  float* COR = W + off; off += (size_t)256*NCB;
  float* COI = W + off; off += (size_t)256*NCB;

  k_init<<<64, 256, 0, stream>>>(TXC,TXS,TTC,TTS,ITC,ITS,WT0,WT1,WTC, fc0_w, fc1_w, wconv);

  const int nch = NBTOT / nb;
  for (int ch = 0; ch < nch; ch++){
    int b0 = ch*nb;
    k_fc0<<<dim3((XT+255)/256, nb), 256, 0, stream>>>(u, xg, tg, par, WT0, fc0_b, VA, b0);
    for (int l=0; l<4; l++){
      k_dftx<<<NCB, 64, 0, stream>>>(VA, TXC, TXS, VXR, VXI);
      k_dftt<<<NCB, 256, 0, stream>>>(VXR, VXI, TTC, TTS, CVR, CVI, NCB);
      k_spec<<<256, 256, 0, stream>>>(swr, swi, CVR, CVI, COR, COI, l, NCB);
      k_conv<<<dim3(53, nb), 256, 0, stream>>>(VA, WTC, wbias, l);
      if (l < 3) k_inv<1><<<NCB, 128, 0, stream>>>(COR, COI, TXC, TXS, ITC, ITS, VA, NCB);
      else       k_inv<0><<<NCB, 128, 0, stream>>>(COR, COI, TXC, TXS, ITC, ITS, VA, NCB);
    }
    k_final<<<dim3(80, nb), 256, 0, stream>>>(VA, WT1, fc1_b, fc2_w, fc2_b, (float*)d_out, b0);
  }
}

// Round 4
// 2864.574 us; speedup vs baseline: 1.6570x; 1.6570x over previous
//
#include <hip/hip_runtime.h>
#include <math.h>

#define XDIM 521
#define TDIM 49
#define TPAD 52
#define XT (XDIM*TPAD)   /* 27092 */
#define NBTOT 32
#define NC 64
#define NS 512
#define NTO 40
#define NTIN 10
#define CIN 14
#define PI_D 3.14159265358979323846

__device__ __forceinline__ float gelu_f(float x){
  return 0.5f*x*(1.0f + erff(x*0.70710678118654752440f));
}

// ---------------- init: twiddle tables + small transposed weight copies ----------------
__global__ void k_init(float* __restrict__ TXC, float* __restrict__ TXS,
                       float* __restrict__ TTC, float* __restrict__ TTS,
                       float* __restrict__ ITC, float* __restrict__ ITS,
                       float* __restrict__ WT0, float* __restrict__ WT1, float* __restrict__ WTC,
                       const float* __restrict__ fc0_w, const float* __restrict__ fc1_w,
                       const float* __restrict__ w_conv){
  int i = blockIdx.x*256 + threadIdx.x;
  if (i < XDIM*16){
    int x = i >> 4, kx = i & 15;
    double ang = 2.0*PI_D*(double)((x*kx)%XDIM)/(double)XDIM;
    TXC[i] = (float)cos(ang);
    TXS[i] = (float)sin(ang);
  }
  if (i < TDIM*16){
    int t = i >> 4, kt = i & 15;
    double ang = 2.0*PI_D*(double)((t*kt)%TDIM)/(double)TDIM;
    TTC[i] = (float)cos(ang);
    TTS[i] = (float)sin(ang);
    double nrm = ((kt==0)?1.0:2.0)/(double)(XDIM*TDIM);
    ITC[i] = (float)(nrm*cos(ang));
    ITS[i] = (float)(nrm*sin(ang));
  }
  if (i < 64*16){               // fc0_w (14,64) -> WT0[c][16]
    int c = i >> 4, k = i & 15;
    WT0[i] = (k < CIN) ? fc0_w[k*64 + c] : 0.f;
  }
  if (i < 128*64){              // fc1_w (64,128) -> WT1[j][c]
    int j = i >> 6, c = i & 63;
    WT1[i] = fc1_w[c*128 + j];
  }
  if (i < 4*64*64){             // w_conv (4,o,c) -> WTC[l][c][o]
    int l = i >> 12, r = i & 4095, c = r >> 6, o = r & 63;
    WTC[i] = w_conv[(l*64 + o)*64 + c];
  }
}

// ---------------- fc0 + grid-feature build + transpose + pad (writes chunk VA) ----------------
__global__ void k_fc0(const float* __restrict__ u, const float* __restrict__ xg,
                      const float* __restrict__ tg, const float* __restrict__ par,
                      const float* __restrict__ WT0, const float* __restrict__ fc0_b,
                      float* __restrict__ v, int b0){
  int bl = blockIdx.y;          // local batch within chunk
  int b  = b0 + bl;             // global batch
  int p = blockIdx.x*256 + threadIdx.x;
  if (p >= XT) return;
  int x = p / TPAD, t = p - x*TPAD;
  bool valid = (x < NS) && (t < NTO);
  float in[CIN];
  if (valid){
    #pragma unroll
    for (int k=0;k<NTIN;k++) in[k] = u[((size_t)(b*NS+x))*NTIN + k];
    in[10] = par[b*2+0]; in[11] = par[b*2+1];
    in[12] = xg[b*NS + x];
    in[13] = tg[b*NTO + t];
  } else {
    #pragma unroll
    for (int k=0;k<CIN;k++) in[k] = 0.f;
  }
  size_t base = ((size_t)bl*NC)*XT + p;
  for (int c=0;c<NC;c++){
    float acc = valid ? fc0_b[c] : 0.f;
    #pragma unroll
    for (int k=0;k<CIN;k++) acc = fmaf(in[k], WT0[c*16+k], acc);
    v[base + (size_t)c*XT] = acc;
  }
}

// ---------------- forward DFT over X (contract 521 -> 16 modes) ----------------
__global__ void __launch_bounds__(64) k_dftx(const float* __restrict__ v,
    const float* __restrict__ TXC, const float* __restrict__ TXS,
    float* __restrict__ VxR, float* __restrict__ VxI){
  int bo = blockIdx.x;
  int t = threadIdx.x;
  const float* vb = v + (size_t)bo*XT;
  bool act = (t < TDIM);
  float ar[16], ai[16];
  #pragma unroll
  for (int k=0;k<16;k++){ ar[k]=0.f; ai[k]=0.f; }
  #pragma unroll 2
  for (int x=0; x<XDIM; x++){
    float vv = act ? vb[(size_t)x*TPAD + t] : 0.f;
    #pragma unroll
    for (int kx=0;kx<16;kx++){
      ar[kx] = fmaf(vv,  TXC[x*16+kx], ar[kx]);
      ai[kx] = fmaf(-vv, TXS[x*16+kx], ai[kx]);
    }
  }
  if (act){
    #pragma unroll
    for (int kx=0;kx<16;kx++){
      VxR[((size_t)bo*16+kx)*TDIM + t] = ar[kx];
      VxI[((size_t)bo*16+kx)*TDIM + t] = ai[kx];
    }
  }
}

// ---------------- forward DFT over T (49 -> 16 modes), complex ----------------
__global__ void k_dftt(const float* __restrict__ VxR, const float* __restrict__ VxI,
                       const float* __restrict__ TTC, const float* __restrict__ TTS,
                       float* __restrict__ cVR, float* __restrict__ cVI, int NCB){
  int bo = blockIdx.x;
  __shared__ float lr[784], li[784];
  for (int q = threadIdx.x; q < 784; q += 256){ lr[q] = VxR[(size_t)bo*784+q]; li[q] = VxI[(size_t)bo*784+q]; }
  __syncthreads();
  int kx = threadIdx.x >> 4, kt = threadIdx.x & 15;
  float accR=0.f, accI=0.f;
  for (int tt=0;tt<TDIM;tt++){
    float vr = lr[kx*TDIM+tt], vi = li[kx*TDIM+tt];
    float c = TTC[tt*16+kt], s = TTS[tt*16+kt];
    accR += vr*c + vi*s;
    accI += vi*c - vr*s;
  }
  int m = kx*16+kt;
  cVR[(size_t)m*NCB + bo] = accR;
  cVI[(size_t)m*NCB + bo] = accI;
}

// ---------------- per-mode 64x64 complex channel mix (weights read in-place) ----------------
__global__ void k_spec(const float* __restrict__ swr, const float* __restrict__ swi,
                       const float* __restrict__ cVR, const float* __restrict__ cVI,
                       float* __restrict__ cOR, float* __restrict__ cOI, int l, int NCB){
  int m = blockIdx.x;           // 0..255 = kx*16+kt
  __shared__ float wr[4096], wi[4096];
  __shared__ float vr[32*65], vi[32*65];
  const size_t wb = (size_t)l*64*64*256 + m;
  for (int q = threadIdx.x; q < 4096; q += 256){
    wr[q] = swr[wb + (size_t)q*256];
    wi[q] = swi[wb + (size_t)q*256];
  }
  for (int q = threadIdx.x; q < NCB; q += 256){
    int b=q>>6, i=q&63;
    vr[b*65+i] = cVR[(size_t)m*NCB+q];
    vi[b*65+i] = cVI[(size_t)m*NCB+q];
  }
  __syncthreads();
  int b = threadIdx.x >> 3, og = threadIdx.x & 7;
  if (b*64 < NCB){
    float oR[8], oI[8];
    #pragma unroll
    for (int j=0;j<8;j++){ oR[j]=0.f; oI[j]=0.f; }
    for (int i=0;i<64;i++){
      float arv = vr[b*65+i], aiv = vi[b*65+i];
      #pragma unroll
      for (int j=0;j<8;j++){
        float wrv = wr[i*64 + og*8 + j], wiv = wi[i*64 + og*8 + j];
        oR[j] = fmaf(arv,wrv,fmaf(-aiv,wiv,oR[j]));
        oI[j] = fmaf(arv,wiv,fmaf( aiv,wrv,oI[j]));
      }
    }
    #pragma unroll
    for (int j=0;j<8;j++){
      cOR[(size_t)m*NCB + b*64 + og*8 + j] = oR[j];
      cOI[(size_t)m*NCB + b*64 + og*8 + j] = oI[j];
    }
  }
}

// ---------------- inverse part 1: kt -> t expansion (tiny), G into dead VX buffers ----------------
__global__ void __launch_bounds__(256) k_invG(const float* __restrict__ cOR, const float* __restrict__ cOI,
    const float* __restrict__ ITC, const float* __restrict__ ITS,
    float* __restrict__ GR, float* __restrict__ GI, int NCB){
  int bo = blockIdx.x;
  __shared__ float lcr[256], lci[256];
  int q = threadIdx.x;
  lcr[q] = cOR[(size_t)q*NCB + bo];
  lci[q] = cOI[(size_t)q*NCB + bo];
  __syncthreads();
  int kx = q >> 4, tq = q & 15;
  for (int t = tq; t < TDIM; t += 16){
    float gr=0.f, gi=0.f;
    #pragma unroll
    for (int kt=0;kt<16;kt++){
      float cr = lcr[kx*16+kt], ci = lci[kx*16+kt];
      float wc = ITC[t*16+kt], ws = ITS[t*16+kt];
      gr = fmaf(cr,wc,fmaf(-ci,ws,gr));
      gi = fmaf(cr,ws,fmaf( ci,wc,gi));
    }
    GR[(size_t)bo*784 + kx*TDIM + t] = gr;
    GI[(size_t)bo*784 + kx*TDIM + t] = gi;
  }
}

// ---------------- inverse part 2: kx -> x expansion + RMW: v = [gelu](u2 + u1) ----------------
// per plane: 4 waves, lane = t, G in registers, twiddles wave-uniform -> s_load
template<int GELU>
__global__ void __launch_bounds__(256) k_inv2(const float* __restrict__ GR, const float* __restrict__ GI,
    const float* __restrict__ TXC, const float* __restrict__ TXS,
    float* __restrict__ v){
  int bo = blockIdx.x;
  int w = threadIdx.x >> 6;
  int t = threadIdx.x & 63;
  bool act = (t < TDIM);
  int tc = act ? t : 0;
  float gr[16], gi[16];
  #pragma unroll
  for (int kx=0;kx<16;kx++){
    gr[kx] = GR[(size_t)bo*784 + kx*TDIM + tc];
    gi[kx] = GI[(size_t)bo*784 + kx*TDIM + tc];
  }
  int x0 = w*131;
  int x1 = min(x0+131, XDIM);
  float* vb = v + (size_t)bo*XT;
  for (int x=x0; x<x1; x++){
    float acc = 0.f;
    #pragma unroll
    for (int kx=0;kx<16;kx++){
      acc = fmaf(gr[kx],  TXC[x*16+kx], acc);   // x wave-uniform -> scalar loads
      acc = fmaf(-gi[kx], TXS[x*16+kx], acc);
    }
    float r = 0.f;
    if (act){
      r = acc + vb[(size_t)x*TPAD + t];
      if (GELU) r = gelu_f(r);
    }
    if (t < TPAD) vb[(size_t)x*TPAD + t] = r;   // slack cols t=49..51 -> 0
  }
}

// ---------------- pointwise conv, IN-PLACE: v <- W*v + bias (u2 stored) ----------------
__global__ void __launch_bounds__(256) k_conv(float* __restrict__ v,
    const float* __restrict__ WTC, const float* __restrict__ w_bias, int l){
  int bl = blockIdx.y;
  int p = blockIdx.x*512 + threadIdx.x*2;
  if (p >= XT) return;
  const float* wl = WTC + l*4096;    // [c][o]
  float a0[64], a1[64];
  #pragma unroll
  for (int o=0;o<64;o++){ a0[o]=0.f; a1[o]=0.f; }
  const size_t bb = (size_t)bl*NC*XT;
  for (int c=0;c<NC;c++){
    const float2 vv = *reinterpret_cast<const float2*>(v + bb + (size_t)c*XT + p);
    #pragma unroll
    for (int o=0;o<64;o++){
      float wv = wl[c*64+o];          // uniform -> s_load
      a0[o] = fmaf(vv.x, wv, a0[o]);
      a1[o] = fmaf(vv.y, wv, a1[o]);
    }
  }
  #pragma unroll
  for (int o=0;o<64;o++){
    float bias = w_bias[l*64+o];
    float2 rr; rr.x = a0[o]+bias; rr.y = a1[o]+bias;
    *reinterpret_cast<float2*>(v + bb + (size_t)o*XT + p) = rr;
  }
}

// ---------------- crop + fc1 + gelu + fc2 ----------------
__global__ void k_final(const float* __restrict__ v, const float* __restrict__ WT1,
                        const float* __restrict__ fc1_b, const float* __restrict__ fc2_w,
                        const float* __restrict__ fc2_b, float* __restrict__ out, int b0){
  int bl = blockIdx.y;
  int pp = blockIdx.x*256 + threadIdx.x;    // 512*40 = 20480 exactly
  int s = pp / NTO, to = pp - s*NTO;
  float vr[64];
  size_t vb = (size_t)bl*NC*XT + (size_t)s*TPAD + to;
  #pragma unroll
  for (int c=0;c<64;c++) vr[c] = v[vb + (size_t)c*XT];
  float acc = fc2_b[0];
  for (int j=0;j<128;j++){
    float h = fc1_b[j];
    #pragma unroll
    for (int c=0;c<64;c++) h = fmaf(vr[c], WT1[j*64+c], h);   // uniform -> s_load
    h = gelu_f(h);
    acc = fmaf(h, fc2_w[j], acc);
  }
  out[((size_t)(b0+bl))*20480 + pp] = acc;
}

extern "C" void kernel_launch(void* const* d_in, const int* in_sizes, int n_in,
                              void* d_out, int out_size, void* d_ws, size_t ws_size,
                              hipStream_t stream){
  const float* u     = (const float*)d_in[0];
  const float* xg    = (const float*)d_in[1];
  const float* tg    = (const float*)d_in[2];
  const float* par   = (const float*)d_in[3];
  const float* fc0_w = (const float*)d_in[4];
  const float* fc0_b = (const float*)d_in[5];
  const float* swr   = (const float*)d_in[6];
  const float* swi   = (const float*)d_in[7];
  const float* wconv = (const float*)d_in[8];
  const float* wbias = (const float*)d_in[9];
  const float* fc1_w = (const float*)d_in[10];
  const float* fc1_b = (const float*)d_in[11];
  const float* fc2_w = (const float*)d_in[12];
  const float* fc2_b = (const float*)d_in[13];

  // pick largest batch chunk whose workspace fits ws_size (same formula as round 3)
  int nb = NBTOT;
  while (nb > 1){
    size_t need = (45408ull + (size_t)nb*64ull*29684ull) * 4ull;
    if (need <= ws_size) break;
    nb >>= 1;
  }
  const int NCB = nb*64;

  float* W = (float*)d_ws;
  size_t off = 0;
  float* TXC = W + off; off += 8336;
  float* TXS = W + off; off += 8336;
  float* TTC = W + off; off += 784;
  float* TTS = W + off; off += 784;
  float* ITC = W + off; off += 784;
  float* ITS = W + off; off += 784;
  float* WT0 = W + off; off += 1024;
  float* WT1 = W + off; off += 8192;
  float* WTC = W + off; off += 16384;
  float* VA  = W + off; off += (size_t)NCB*XT;
  float* VXR = W + off; off += (size_t)NCB*784;   // reused as GR after k_dftt
  float* VXI = W + off; off += (size_t)NCB*784;   // reused as GI after k_dftt
  float* CVR = W + off; off += (size_t)256*NCB;
  float* CVI = W + off; off += (size_t)256*NCB;
  float* COR = W + off; off += (size_t)256*NCB;
  float* COI = W + off; off += (size_t)256*NCB;

  k_init<<<64, 256, 0, stream>>>(TXC,TXS,TTC,TTS,ITC,ITS,WT0,WT1,WTC, fc0_w, fc1_w, wconv);

  const int nch = NBTOT / nb;
  for (int ch = 0; ch < nch; ch++){
    int b0 = ch*nb;
    k_fc0<<<dim3((XT+255)/256, nb), 256, 0, stream>>>(u, xg, tg, par, WT0, fc0_b, VA, b0);
    for (int l=0; l<4; l++){
      k_dftx<<<NCB, 64, 0, stream>>>(VA, TXC, TXS, VXR, VXI);
      k_dftt<<<NCB, 256, 0, stream>>>(VXR, VXI, TTC, TTS, CVR, CVI, NCB);
      k_spec<<<256, 256, 0, stream>>>(swr, swi, CVR, CVI, COR, COI, l, NCB);
      k_invG<<<NCB, 256, 0, stream>>>(COR, COI, ITC, ITS, VXR, VXI, NCB);
      k_conv<<<dim3(53, nb), 256, 0, stream>>>(VA, WTC, wbias, l);
      if (l < 3) k_inv2<1><<<NCB, 256, 0, stream>>>(VXR, VXI, TXC, TXS, VA);
      else       k_inv2<0><<<NCB, 256, 0, stream>>>(VXR, VXI, TXC, TXS, VA);
    }
    k_final<<<dim3(80, nb), 256, 0, stream>>>(VA, WT1, fc1_b, fc2_w, fc2_b, (float*)d_out, b0);
  }
}

// Round 5
// 2415.724 us; speedup vs baseline: 1.9649x; 1.1858x over previous
//
#include <hip/hip_runtime.h>
#include <math.h>

#define XDIM 521
#define TDIM 49
#define TPAD 52
#define XT (XDIM*TPAD)   /* 27092 */
#define NBTOT 32
#define NC 64
#define NS 512
#define NTO 40
#define NTIN 10
#define CIN 14
#define PI_D 3.14159265358979323846

__device__ __forceinline__ float gelu_f(float x){
  return 0.5f*x*(1.0f + erff(x*0.70710678118654752440f));
}

// ---------------- init: twiddle tables + small transposed weight copies ----------------
__global__ void k_init(float* __restrict__ TXC, float* __restrict__ TXS,
                       float* __restrict__ TTC, float* __restrict__ TTS,
                       float* __restrict__ ITC, float* __restrict__ ITS,
                       float* __restrict__ WT0, float* __restrict__ WT1, float* __restrict__ WTC,
                       const float* __restrict__ fc0_w, const float* __restrict__ fc1_w,
                       const float* __restrict__ w_conv){
  int i = blockIdx.x*256 + threadIdx.x;
  if (i < XDIM*16){
    int x = i >> 4, kx = i & 15;
    double ang = 2.0*PI_D*(double)((x*kx)%XDIM)/(double)XDIM;
    TXC[i] = (float)cos(ang);
    TXS[i] = (float)sin(ang);
  }
  if (i < TDIM*16){
    int t = i >> 4, kt = i & 15;
    double ang = 2.0*PI_D*(double)((t*kt)%TDIM)/(double)TDIM;
    TTC[i] = (float)cos(ang);
    TTS[i] = (float)sin(ang);
    double nrm = ((kt==0)?1.0:2.0)/(double)(XDIM*TDIM);
    ITC[i] = (float)(nrm*cos(ang));
    ITS[i] = (float)(nrm*sin(ang));
  }
  if (i < 64*16){               // fc0_w (14,64) -> WT0[c][16]
    int c = i >> 4, k = i & 15;
    WT0[i] = (k < CIN) ? fc0_w[k*64 + c] : 0.f;
  }
  if (i < 128*64){              // fc1_w (64,128) -> WT1[j][c]
    int j = i >> 6, c = i & 63;
    WT1[i] = fc1_w[c*128 + j];
  }
  if (i < 4*64*64){             // w_conv (4,o,c) -> WTC[l][c][o]
    int l = i >> 12, r = i & 4095, c = r >> 6, o = r & 63;
    WTC[i] = w_conv[(l*64 + o)*64 + c];
  }
}

// ---- shared tail: reduce 4-wave DFT-x partials, apply T-DFT, emit cV (transposed) ----
__device__ __forceinline__ void dft_reduce_emit(
    float (&ar)[16], float (&ai)[16], int w, int t,
    const float* __restrict__ TTC, const float* __restrict__ TTS,
    float* __restrict__ cVR, float* __restrict__ cVI, int bo, int NCB){
  __shared__ float redR[4*16*50], redI[4*16*50];
  if (t < TDIM){
    #pragma unroll
    for (int kx=0;kx<16;kx++){
      redR[(w*16+kx)*50 + t] = ar[kx];
      redI[(w*16+kx)*50 + t] = ai[kx];
    }
  }
  __syncthreads();
  int tid = w*64 + t;
  // combine wave partials (each q owned by exactly one thread: no extra sync needed)
  for (int q = tid; q < 784; q += 256){
    int kx = q/49, tt = q - kx*49;
    int idx = kx*50 + tt;
    float sR = redR[idx] + redR[800+idx] + redR[1600+idx] + redR[2400+idx];
    float sI = redI[idx] + redI[800+idx] + redI[1600+idx] + redI[2400+idx];
    redR[idx] = sR; redI[idx] = sI;
  }
  __syncthreads();
  // T-DFT: thread tid = kx*16+kt
  int kx = tid >> 4, kt = tid & 15;
  float accR=0.f, accI=0.f;
  for (int tt=0; tt<TDIM; tt++){
    float vr = redR[kx*50+tt], vi = redI[kx*50+tt];
    float c = TTC[tt*16+kt], s = TTS[tt*16+kt];
    accR += vr*c + vi*s;
    accI += vi*c - vr*s;
  }
  cVR[(size_t)tid*NCB + bo] = accR;
  cVI[(size_t)tid*NCB + bo] = accI;
}

// ---------------- fused fc0 + DFT-x + DFT-t (block = one (bl,c) plane) ----------------
__global__ void __launch_bounds__(256) k_fc0dft(const float* __restrict__ u, const float* __restrict__ xg,
    const float* __restrict__ tg, const float* __restrict__ par,
    const float* __restrict__ WT0, const float* __restrict__ fc0_b,
    const float* __restrict__ TXC, const float* __restrict__ TXS,
    const float* __restrict__ TTC, const float* __restrict__ TTS,
    float* __restrict__ v, float* __restrict__ cVR, float* __restrict__ cVI,
    int b0, int NCB){
  int bo = blockIdx.x;
  int bl = bo >> 6, c = bo & 63;
  int b = b0 + bl;
  int w = threadIdx.x >> 6, t = threadIdx.x & 63;
  float tgv = (t < NTO) ? tg[b*NTO + t] : 0.f;
  float w0[CIN];
  #pragma unroll
  for (int k=0;k<CIN;k++) w0[k] = WT0[c*16+k];       // uniform -> s_load
  float base_u = fc0_b[c] + par[b*2]*w0[10] + par[b*2+1]*w0[11] + tgv*w0[13];
  float ar[16], ai[16];
  #pragma unroll
  for (int k=0;k<16;k++){ ar[k]=0.f; ai[k]=0.f; }
  float* vb = v + (size_t)bo*XT;
  int x0 = w*131, x1 = min(x0+131, XDIM);
  for (int x=x0; x<x1; x++){
    float val = 0.f;
    if (x < NS && t < NTO){
      float acc = base_u + xg[b*NS+x]*w0[12];
      #pragma unroll
      for (int k=0;k<NTIN;k++) acc = fmaf(u[((size_t)(b*NS+x))*NTIN + k], w0[k], acc);
      val = acc;
    }
    if (t < TPAD) vb[(size_t)x*TPAD + t] = val;
    #pragma unroll
    for (int kx=0;kx<16;kx++){
      float tc = TXC[x*16+kx], ts = TXS[x*16+kx];    // uniform -> s_load
      ar[kx] = fmaf(val,  tc, ar[kx]);
      ai[kx] = fmaf(-val, ts, ai[kx]);
    }
  }
  dft_reduce_emit(ar, ai, w, t, TTC, TTS, cVR, cVI, bo, NCB);
}

// ---------------- per-mode 64x64 complex channel mix (weights read in-place) ----------------
__global__ void k_spec(const float* __restrict__ swr, const float* __restrict__ swi,
                       const float* __restrict__ cVR, const float* __restrict__ cVI,
                       float* __restrict__ cOR, float* __restrict__ cOI, int l, int NCB){
  int m = blockIdx.x;           // 0..255 = kx*16+kt
  __shared__ float wr[4096], wi[4096];
  __shared__ float vr[32*65], vi[32*65];
  const size_t wb = (size_t)l*64*64*256 + m;
  for (int q = threadIdx.x; q < 4096; q += 256){
    wr[q] = swr[wb + (size_t)q*256];
    wi[q] = swi[wb + (size_t)q*256];
  }
  for (int q = threadIdx.x; q < NCB; q += 256){
    int b=q>>6, i=q&63;
    vr[b*65+i] = cVR[(size_t)m*NCB+q];
    vi[b*65+i] = cVI[(size_t)m*NCB+q];
  }
  __syncthreads();
  int b = threadIdx.x >> 3, og = threadIdx.x & 7;
  if (b*64 < NCB){
    float oR[8], oI[8];
    #pragma unroll
    for (int j=0;j<8;j++){ oR[j]=0.f; oI[j]=0.f; }
    for (int i=0;i<64;i++){
      float arv = vr[b*65+i], aiv = vi[b*65+i];
      #pragma unroll
      for (int j=0;j<8;j++){
        float wrv = wr[i*64 + og*8 + j], wiv = wi[i*64 + og*8 + j];
        oR[j] = fmaf(arv,wrv,fmaf(-aiv,wiv,oR[j]));
        oI[j] = fmaf(arv,wiv,fmaf( aiv,wrv,oI[j]));
      }
    }
    #pragma unroll
    for (int j=0;j<8;j++){
      cOR[(size_t)m*NCB + b*64 + og*8 + j] = oR[j];
      cOI[(size_t)m*NCB + b*64 + og*8 + j] = oI[j];
    }
  }
}

// ---------------- inverse part 1: kt -> t expansion (tiny), G into VX buffers ----------------
__global__ void __launch_bounds__(256) k_invG(const float* __restrict__ cOR, const float* __restrict__ cOI,
    const float* __restrict__ ITC, const float* __restrict__ ITS,
    float* __restrict__ GR, float* __restrict__ GI, int NCB){
  int bo = blockIdx.x;
  __shared__ float lcr[256], lci[256];
  int q = threadIdx.x;
  lcr[q] = cOR[(size_t)q*NCB + bo];
  lci[q] = cOI[(size_t)q*NCB + bo];
  __syncthreads();
  int kx = q >> 4, tq = q & 15;
  for (int t = tq; t < TDIM; t += 16){
    float gr=0.f, gi=0.f;
    #pragma unroll
    for (int kt=0;kt<16;kt++){
      float cr = lcr[kx*16+kt], ci = lci[kx*16+kt];
      float wc = ITC[t*16+kt], ws = ITS[t*16+kt];
      gr = fmaf(cr,wc,fmaf(-ci,ws,gr));
      gi = fmaf(cr,ws,fmaf( ci,wc,gi));
    }
    GR[(size_t)bo*784 + kx*TDIM + t] = gr;
    GI[(size_t)bo*784 + kx*TDIM + t] = gi;
  }
}

// ---------------- pointwise conv, IN-PLACE: v <- W*v + bias (u2 stored) ----------------
__global__ void __launch_bounds__(256) k_conv(float* __restrict__ v,
    const float* __restrict__ WTC, const float* __restrict__ w_bias, int l){
  int bl = blockIdx.y;
  int p = blockIdx.x*512 + threadIdx.x*2;
  if (p >= XT) return;
  const float* wl = WTC + l*4096;    // [c][o]
  float a0[64], a1[64];
  #pragma unroll
  for (int o=0;o<64;o++){ a0[o]=0.f; a1[o]=0.f; }
  const size_t bb = (size_t)bl*NC*XT;
  for (int c=0;c<NC;c++){
    const float2 vv = *reinterpret_cast<const float2*>(v + bb + (size_t)c*XT + p);
    #pragma unroll
    for (int o=0;o<64;o++){
      float wv = wl[c*64+o];          // uniform -> s_load
      a0[o] = fmaf(vv.x, wv, a0[o]);
      a1[o] = fmaf(vv.y, wv, a1[o]);
    }
  }
  #pragma unroll
  for (int o=0;o<64;o++){
    float bias = w_bias[l*64+o];
    float2 rr; rr.x = a0[o]+bias; rr.y = a1[o]+bias;
    *reinterpret_cast<float2*>(v + bb + (size_t)o*XT + p) = rr;
  }
}

// ---------------- fused inverse-x + add + gelu + next-layer DFT-x/DFT-t ----------------
// block = one plane; v holds u2 (conv output); v <- [gelu](u1 + u2); if EMIT, emits cV
template<int GELU, int EMIT>
__global__ void __launch_bounds__(256) k_inv2dft(const float* __restrict__ GR, const float* __restrict__ GI,
    const float* __restrict__ TXC, const float* __restrict__ TXS,
    const float* __restrict__ TTC, const float* __restrict__ TTS,
    float* __restrict__ v, float* __restrict__ cVR, float* __restrict__ cVI, int NCB){
  int bo = blockIdx.x;
  int w = threadIdx.x >> 6, t = threadIdx.x & 63;
  bool act = (t < TDIM);
  int tc = act ? t : 0;
  float gr[16], gi[16];
  #pragma unroll
  for (int kx=0;kx<16;kx++){
    gr[kx] = GR[(size_t)bo*784 + kx*TDIM + tc];
    gi[kx] = GI[(size_t)bo*784 + kx*TDIM + tc];
  }
  float ar[16], ai[16];
  #pragma unroll
  for (int k=0;k<16;k++){ ar[k]=0.f; ai[k]=0.f; }
  float* vb = v + (size_t)bo*XT;
  int x0 = w*131, x1 = min(x0+131, XDIM);
  for (int x=x0; x<x1; x++){
    float tc16[16], ts16[16];
    #pragma unroll
    for (int kx=0;kx<16;kx++){ tc16[kx] = TXC[x*16+kx]; ts16[kx] = TXS[x*16+kx]; } // s_load
    float acc = 0.f;
    #pragma unroll
    for (int kx=0;kx<16;kx++){
      acc = fmaf(gr[kx],  tc16[kx], acc);
      acc = fmaf(-gi[kx], ts16[kx], acc);
    }
    float r = 0.f;
    if (act){
      r = acc + vb[(size_t)x*TPAD + t];
      if (GELU) r = gelu_f(r);
    }
    if (t < TPAD) vb[(size_t)x*TPAD + t] = r;
    if (EMIT){
      #pragma unroll
      for (int kx=0;kx<16;kx++){
        ar[kx] = fmaf(r,  tc16[kx], ar[kx]);
        ai[kx] = fmaf(-r, ts16[kx], ai[kx]);
      }
    }
  }
  if (EMIT) dft_reduce_emit(ar, ai, w, t, TTC, TTS, cVR, cVI, bo, NCB);
}

// ---------------- crop + fc1 + gelu + fc2 ----------------
__global__ void k_final(const float* __restrict__ v, const float* __restrict__ WT1,
                        const float* __restrict__ fc1_b, const float* __restrict__ fc2_w,
                        const float* __restrict__ fc2_b, float* __restrict__ out, int b0){
  int bl = blockIdx.y;
  int pp = blockIdx.x*256 + threadIdx.x;    // 512*40 = 20480 exactly
  int s = pp / NTO, to = pp - s*NTO;
  float vr[64];
  size_t vb = (size_t)bl*NC*XT + (size_t)s*TPAD + to;
  #pragma unroll
  for (int c=0;c<64;c++) vr[c] = v[vb + (size_t)c*XT];
  float acc = fc2_b[0];
  for (int j=0;j<128;j++){
    float h = fc1_b[j];
    #pragma unroll
    for (int c=0;c<64;c++) h = fmaf(vr[c], WT1[j*64+c], h);   // uniform -> s_load
    h = gelu_f(h);
    acc = fmaf(h, fc2_w[j], acc);
  }
  out[((size_t)(b0+bl))*20480 + pp] = acc;
}

extern "C" void kernel_launch(void* const* d_in, const int* in_sizes, int n_in,
                              void* d_out, int out_size, void* d_ws, size_t ws_size,
                              hipStream_t stream){
  const float* u     = (const float*)d_in[0];
  const float* xg    = (const float*)d_in[1];
  const float* tg    = (const float*)d_in[2];
  const float* par   = (const float*)d_in[3];
  const float* fc0_w = (const float*)d_in[4];
  const float* fc0_b = (const float*)d_in[5];
  const float* swr   = (const float*)d_in[6];
  const float* swi   = (const float*)d_in[7];
  const float* wconv = (const float*)d_in[8];
  const float* wbias = (const float*)d_in[9];
  const float* fc1_w = (const float*)d_in[10];
  const float* fc1_b = (const float*)d_in[11];
  const float* fc2_w = (const float*)d_in[12];
  const float* fc2_b = (const float*)d_in[13];

  // pick largest batch chunk whose workspace fits ws_size (same formula as round 4)
  int nb = NBTOT;
  while (nb > 1){
    size_t need = (45408ull + (size_t)nb*64ull*29684ull) * 4ull;
    if (need <= ws_size) break;
    nb >>= 1;
  }
  const int NCB = nb*64;

  float* W = (float*)d_ws;
  size_t off = 0;
  float* TXC = W + off; off += 8336;
  float* TXS = W + off; off += 8336;
  float* TTC = W + off; off += 784;
  float* TTS = W + off; off += 784;
  float* ITC = W + off; off += 784;
  float* ITS = W + off; off += 784;
  float* WT0 = W + off; off += 1024;
  float* WT1 = W + off; off += 8192;
  float* WTC = W + off; off += 16384;
  float* VA  = W + off; off += (size_t)NCB*XT;
  float* VXR = W + off; off += (size_t)NCB*784;   // G real
  float* VXI = W + off; off += (size_t)NCB*784;   // G imag
  float* CVR = W + off; off += (size_t)256*NCB;
  float* CVI = W + off; off += (size_t)256*NCB;
  float* COR = W + off; off += (size_t)256*NCB;
  float* COI = W + off; off += (size_t)256*NCB;

  k_init<<<64, 256, 0, stream>>>(TXC,TXS,TTC,TTS,ITC,ITS,WT0,WT1,WTC, fc0_w, fc1_w, wconv);

  const int nch = NBTOT / nb;
  for (int ch = 0; ch < nch; ch++){
    int b0 = ch*nb;
    k_fc0dft<<<NCB, 256, 0, stream>>>(u, xg, tg, par, WT0, fc0_b, TXC, TXS, TTC, TTS,
                                      VA, CVR, CVI, b0, NCB);
    for (int l=0; l<4; l++){
      k_spec<<<256, 256, 0, stream>>>(swr, swi, CVR, CVI, COR, COI, l, NCB);
      k_invG<<<NCB, 256, 0, stream>>>(COR, COI, ITC, ITS, VXR, VXI, NCB);
      k_conv<<<dim3(53, nb), 256, 0, stream>>>(VA, WTC, wbias, l);
      if (l < 3) k_inv2dft<1,1><<<NCB, 256, 0, stream>>>(VXR, VXI, TXC, TXS, TTC, TTS, VA, CVR, CVI, NCB);
      else       k_inv2dft<0,0><<<NCB, 256, 0, stream>>>(VXR, VXI, TXC, TXS, TTC, TTS, VA, CVR, CVI, NCB);
    }
    k_final<<<dim3(80, nb), 256, 0, stream>>>(VA, WT1, fc1_b, fc2_w, fc2_b, (float*)d_out, b0);
  }
}